// Round 1
// baseline (357.647 us; speedup 1.0000x reference)
//
#include <hip/hip_runtime.h>
#include <math.h>

#define NBATCH 8
#define HWN (1024*1024)
#define NSEG 16

// ---------- helpers ----------

static __device__ __forceinline__ float polar01(float x, float y) {
    // matches reference: (arctan(y/(x+1e-12)) + (x<0)*pi + ((x>0)&(y<0))*2pi) / (2pi)
    float t = atanf(y / (x + 1e-12f));
    if (x < 0.f) t += 3.14159265358979323846f;
    else if (x > 0.f && y < 0.f) t += 6.28318530717958647692f;
    return t / 6.2831855f;  // 2*float32(pi)
}

// block = 256 threads (4 waves). Result valid in thread 0.
static __device__ __forceinline__ void block_reduce2(double& a, double& b) {
    for (int o = 32; o; o >>= 1) { a += __shfl_down(a, o); b += __shfl_down(b, o); }
    __shared__ double sa[4], sb[4];
    int wave = threadIdx.x >> 6, lane = threadIdx.x & 63;
    if (lane == 0) { sa[wave] = a; sb[wave] = b; }
    __syncthreads();
    if (threadIdx.x == 0) {
        a = sa[0] + sa[1] + sa[2] + sa[3];
        b = sb[0] + sb[1] + sb[2] + sb[3];
    }
    __syncthreads();
}

// ---------- kernels ----------

// per-sample 16-bin histogram of gt
__global__ void k_hist_gt(const int* __restrict__ gt, unsigned* __restrict__ counts) {
    int n = blockIdx.y;
    __shared__ unsigned sh[NSEG];
    if (threadIdx.x < NSEG) sh[threadIdx.x] = 0u;
    __syncthreads();
    const int4* g4 = (const int4*)(gt + (size_t)n * HWN);
    int stride = gridDim.x * blockDim.x;
    for (int j = blockIdx.x * blockDim.x + threadIdx.x; j < HWN / 4; j += stride) {
        int4 g = g4[j];
        atomicAdd(&sh[g.x & 15], 1u);
        atomicAdd(&sh[g.y & 15], 1u);
        atomicAdd(&sh[g.z & 15], 1u);
        atomicAdd(&sh[g.w & 15], 1u);
    }
    __syncthreads();
    if (threadIdx.x < NSEG) atomicAdd(&counts[n * NSEG + threadIdx.x], sh[threadIdx.x]);
}

// per-sample: pix[16], k
__global__ void k_stats(const unsigned* __restrict__ counts, float* __restrict__ pix,
                        int* __restrict__ kv) {
    int n = threadIdx.x;
    if (n >= NBATCH) return;
    unsigned c[NSEG];
    int sumPos = 0, nseg = 0;
#pragma unroll
    for (int s = 0; s < NSEG; ++s) c[s] = counts[n * NSEG + s];
#pragma unroll
    for (int s = 1; s < NSEG; ++s) { sumPos += (int)c[s]; nseg += (c[s] > 0u) ? 1 : 0; }
    int sumNeg = (int)c[0];
    float seg_ave = (float)sumPos / (float)((nseg > 1) ? nseg : 1);
#pragma unroll
    for (int s = 0; s < NSEG; ++s) {
        unsigned cc = (c[s] > 1u) ? c[s] : 1u;
        pix[n * NSEG + s] = seg_ave / (float)cc;
    }
    int k = 3 * sumPos;
    if (sumNeg < k) k = sumNeg;
    kv[n] = k;
}

// fused: term, weight, num1/wsum partials, MSB-16 histogram of nonzero loss
__global__ void k_term(const float* __restrict__ pred, const float* __restrict__ gdf,
                       const int* __restrict__ gt, const float* __restrict__ pix,
                       float* __restrict__ termBuf, unsigned* __restrict__ hist16,
                       double* __restrict__ partA) {
    int n = blockIdx.y;
    __shared__ float spix[NSEG];
    if (threadIdx.x < NSEG) spix[threadIdx.x] = pix[n * NSEG + threadIdx.x];
    __syncthreads();
    int j = blockIdx.x * blockDim.x + threadIdx.x;  // < HWN/4 exactly
    float4 Px = ((const float4*)(pred + ((size_t)n * 2 + 0) * HWN))[j];
    float4 Py = ((const float4*)(pred + ((size_t)n * 2 + 1) * HWN))[j];
    float4 Gx = ((const float4*)(gdf + ((size_t)n * 2 + 0) * HWN))[j];
    float4 Gy = ((const float4*)(gdf + ((size_t)n * 2 + 1) * HWN))[j];
    int4 G = ((const int4*)(gt + (size_t)n * HWN))[j];
    unsigned* hn = hist16 + ((size_t)n << 16);
    float num1 = 0.f, wsum = 0.f;
    float4 T;
#pragma unroll
    for (int e = 0; e < 4; ++e) {
        float px = ((const float*)&Px)[e], py = ((const float*)&Py)[e];
        float gx = ((const float*)&Gx)[e], gy = ((const float*)&Gy)[e];
        int gv = ((const int*)&G)[e];
        float dx = px - gx, dy = py - gy;
        float ang = polar01(gx, gy) - polar01(px, py);
        float t = dx * dx + dy * dy + ang * ang;
        ((float*)&T)[e] = t;
        float w = (gv > 0) ? spix[gv & 15] : 0.f;
        num1 += t * w;
        wsum += w;
        float loss = (w == 0.f) ? t : 0.f;
        unsigned u = __float_as_uint(loss);
        if (u != 0u) atomicAdd(hn + (u >> 16), 1u);
    }
    ((float4*)(termBuf + (size_t)n * HWN))[j] = T;
    double a = (double)num1, b = (double)wsum;
    block_reduce2(a, b);
    if (threadIdx.x == 0) {
        double* p = partA + ((size_t)n * gridDim.x + blockIdx.x) * 2;
        p[0] = a; p[1] = b;
    }
}

// st layout per n: [0]=done, [1]=b16, [2]=k2, [3]=T
__global__ void k_scan1(const unsigned* __restrict__ hist16, const int* __restrict__ kv,
                        unsigned* __restrict__ st) {
    int n = blockIdx.x;
    __shared__ unsigned part[256];
    const unsigned* h = hist16 + ((size_t)n << 16);
    unsigned s = 0;
    for (int jj = 0; jj < 256; ++jj) s += h[threadIdx.x * 256 + jj];
    part[threadIdx.x] = s;
    __syncthreads();
    if (threadIdx.x == 0) {
        int k = kv[n];
        unsigned* stn = st + n * 4;
        if (k <= 0) { stn[0] = 1u; stn[3] = 0xFFFFFFFFu; }
        else {
            unsigned long long cum = 0;
            int seg = -1;
            for (int t = 255; t >= 0; --t) {
                if (cum + (unsigned long long)part[t] >= (unsigned long long)k) { seg = t; break; }
                cum += part[t];
            }
            if (seg < 0) { stn[0] = 1u; stn[3] = 0u; }  // k >= #nonzeros: keep all nonzero
            else {
                unsigned c = (unsigned)cum;
                for (int b = 255; b >= 0; --b) {
                    unsigned hb = h[seg * 256 + b];
                    if (c + hb >= (unsigned)k) {
                        stn[0] = 0u; stn[1] = (unsigned)(seg * 256 + b); stn[2] = (unsigned)k - c;
                        break;
                    }
                    c += hb;
                }
            }
        }
    }
}

__global__ void k_hist2(const float* __restrict__ termBuf, const int* __restrict__ gt,
                        const float* __restrict__ pix, const unsigned* __restrict__ st,
                        unsigned* __restrict__ hist2) {
    int n = blockIdx.y;
    if (st[n * 4 + 0] == 1u) return;  // block-uniform
    unsigned b16 = st[n * 4 + 1];
    __shared__ float spix[NSEG];
    if (threadIdx.x < NSEG) spix[threadIdx.x] = pix[n * NSEG + threadIdx.x];
    __syncthreads();
    int j = blockIdx.x * blockDim.x + threadIdx.x;
    float4 t = ((const float4*)(termBuf + (size_t)n * HWN))[j];
    int4 g = ((const int4*)(gt + (size_t)n * HWN))[j];
    unsigned* hn = hist2 + ((size_t)n << 16);
#pragma unroll
    for (int e = 0; e < 4; ++e) {
        float tv = ((const float*)&t)[e];
        int gv = ((const int*)&g)[e];
        float w = (gv > 0) ? spix[gv & 15] : 0.f;
        float loss = (w == 0.f) ? tv : 0.f;
        unsigned u = __float_as_uint(loss);
        if (u != 0u && (u >> 16) == b16) atomicAdd(hn + (u & 0xFFFFu), 1u);
    }
}

__global__ void k_scan2(const unsigned* __restrict__ hist2, unsigned* __restrict__ st) {
    int n = blockIdx.x;
    if (st[n * 4 + 0] == 1u) return;
    __shared__ unsigned part[256];
    const unsigned* h = hist2 + ((size_t)n << 16);
    unsigned s = 0;
    for (int jj = 0; jj < 256; ++jj) s += h[threadIdx.x * 256 + jj];
    part[threadIdx.x] = s;
    __syncthreads();
    if (threadIdx.x == 0) {
        unsigned k2 = st[n * 4 + 2];
        unsigned b16 = st[n * 4 + 1];
        unsigned cum = 0;
        for (int t = 255; t >= 0; --t) {
            if (cum + part[t] >= k2) {
                unsigned c = cum;
                for (int b = 255; b >= 0; --b) {
                    unsigned hb = h[t * 256 + b];
                    if (c + hb >= k2) { st[n * 4 + 3] = (b16 << 16) | (unsigned)(t * 256 + b); break; }
                    c += hb;
                }
                break;
            }
            cum += part[t];
        }
    }
}

// per (h,w): tsum = sum_n term, msum = sum_n mask; accumulate tsum*msum and msum
__global__ void k_final(const float* __restrict__ termBuf, const int* __restrict__ gt,
                        const float* __restrict__ pix, const unsigned* __restrict__ st,
                        double* __restrict__ partB) {
    __shared__ float spix[NBATCH * NSEG];
    __shared__ unsigned sT[NBATCH];
    if (threadIdx.x < NBATCH * NSEG) spix[threadIdx.x] = pix[threadIdx.x];
    if (threadIdx.x < NBATCH) sT[threadIdx.x] = st[threadIdx.x * 4 + 3];
    __syncthreads();
    int j = blockIdx.x * blockDim.x + threadIdx.x;  // < HWN/4 exactly
    float ts[4] = {0.f, 0.f, 0.f, 0.f}, ms[4] = {0.f, 0.f, 0.f, 0.f};
#pragma unroll
    for (int n = 0; n < NBATCH; ++n) {
        float4 t = ((const float4*)(termBuf + (size_t)n * HWN))[j];
        int4 g = ((const int4*)(gt + (size_t)n * HWN))[j];
        unsigned Tn = sT[n];
#pragma unroll
        for (int e = 0; e < 4; ++e) {
            float tv = ((const float*)&t)[e];
            int gv = ((const int*)&g)[e];
            float w = (gv > 0) ? spix[n * NSEG + (gv & 15)] : 0.f;
            float loss = (w == 0.f) ? tv : 0.f;
            unsigned u = __float_as_uint(loss);
            bool m = (u != 0u) && (u >= Tn);
            ts[e] += tv;
            ms[e] += m ? 1.f : 0.f;
        }
    }
    double c = 0.0, d = 0.0;
#pragma unroll
    for (int e = 0; e < 4; ++e) { c += (double)ts[e] * (double)ms[e]; d += (double)ms[e]; }
    block_reduce2(c, d);
    if (threadIdx.x == 0) {
        double* p = partB + (size_t)blockIdx.x * 2;
        p[0] = c; p[1] = d;
    }
}

__global__ void k_result(const double* __restrict__ partA, const double* __restrict__ partB,
                         float* __restrict__ out) {
    double a = 0, b = 0, c = 0, d = 0;
    for (int i = threadIdx.x; i < NBATCH * 1024; i += 256) { a += partA[2 * i]; b += partA[2 * i + 1]; }
    for (int i = threadIdx.x; i < 1024; i += 256) { c += partB[2 * i]; d += partB[2 * i + 1]; }
    for (int o = 32; o; o >>= 1) {
        a += __shfl_down(a, o); b += __shfl_down(b, o);
        c += __shfl_down(c, o); d += __shfl_down(d, o);
    }
    __shared__ double sa[4], sb[4], sc[4], sd[4];
    int wave = threadIdx.x >> 6, lane = threadIdx.x & 63;
    if (lane == 0) { sa[wave] = a; sb[wave] = b; sc[wave] = c; sd[wave] = d; }
    __syncthreads();
    if (threadIdx.x == 0) {
        double num1 = sa[0] + sa[1] + sa[2] + sa[3];
        double wsum = sb[0] + sb[1] + sb[2] + sb[3];
        double num2 = sc[0] + sc[1] + sc[2] + sc[3];
        double msum = sd[0] + sd[1] + sd[2] + sd[3];
        double num = (double)NBATCH * num1 + num2;
        double denom = (double)NBATCH * (wsum + msum);
        out[0] = (float)(num / (double)NBATCH / 2.0 / denom);
    }
}

// ---------- launcher ----------

extern "C" void kernel_launch(void* const* d_in, const int* in_sizes, int n_in,
                              void* d_out, int out_size, void* d_ws, size_t ws_size,
                              hipStream_t stream) {
    const float* pred = (const float*)d_in[0];
    const float* gdf  = (const float*)d_in[1];
    const int*   gt   = (const int*)d_in[2];
    float* out = (float*)d_out;

    // workspace layout
    const size_t TERM_BYTES = (size_t)NBATCH * HWN * sizeof(float);     // 32 MiB
    const size_t CNT_BYTES  = NBATCH * NSEG * sizeof(unsigned);          // 512
    const size_t H16_BYTES  = (size_t)NBATCH * 65536 * sizeof(unsigned); // 2 MiB
    const size_t ZBYTES     = CNT_BYTES + 2 * H16_BYTES;

    char* W = (char*)d_ws;
    float* termBuf    = (float*)W;
    char* zbase       = W + TERM_BYTES;
    unsigned* counts  = (unsigned*)zbase;
    unsigned* hist16  = (unsigned*)(zbase + CNT_BYTES);
    unsigned* hist2   = (unsigned*)(zbase + CNT_BYTES + H16_BYTES);
    char* p2          = zbase + ZBYTES;
    float* pix        = (float*)p2;                         // 512 B
    int* kv           = (int*)(p2 + 512);                   // 32 B
    unsigned* st      = (unsigned*)(p2 + 544);              // 128 B
    double* partA     = (double*)(p2 + 672);                // 8192*2 doubles
    double* partB     = partA + (size_t)NBATCH * 1024 * 2;  // 1024*2 doubles

    size_t need = TERM_BYTES + ZBYTES + 672 +
                  (size_t)NBATCH * 1024 * 2 * 8 + 1024 * 2 * 8;
    if (ws_size < need) return;  // avoid corrupting memory; will show as wrong answer

    hipMemsetAsync(zbase, 0, ZBYTES, stream);
    k_hist_gt<<<dim3(256, NBATCH), 256, 0, stream>>>(gt, counts);
    k_stats<<<1, 64, 0, stream>>>(counts, pix, kv);
    k_term<<<dim3(1024, NBATCH), 256, 0, stream>>>(pred, gdf, gt, pix, termBuf, hist16, partA);
    k_scan1<<<NBATCH, 256, 0, stream>>>(hist16, kv, st);
    k_hist2<<<dim3(1024, NBATCH), 256, 0, stream>>>(termBuf, gt, pix, st, hist2);
    k_scan2<<<NBATCH, 256, 0, stream>>>(hist2, st);
    k_final<<<1024, 256, 0, stream>>>(termBuf, gt, pix, st, partB);
    k_result<<<1, 256, 0, stream>>>(partA, partB, out);
}

// Round 3
// 212.370 us; speedup vs baseline: 1.6841x; 1.6841x over previous
//
#include <hip/hip_runtime.h>
#include <math.h>

#define NBATCH 8
#define HWN (1024*1024)
#define NGRP (HWN/4)       // float4 groups per sample
#define NSEG 16
#define N2B 512            // k_num2 blocks

// ---------- helpers ----------

static __device__ __forceinline__ float polar01(float x, float y) {
    // reference: (arctan(y/(x+1e-12)) + (x<0)*pi + ((x>0)&(y<0))*2pi) / (2pi)
    float r = y * __builtin_amdgcn_rcpf(x + 1e-12f);
    float ar = fabsf(r);
    float inv = __builtin_amdgcn_rcpf(ar);
    bool big = ar > 1.0f;
    float t = big ? inv : ar;
    float s = t * t;
    float p = -0.0117212f;
    p = fmaf(p, s,  0.05265332f);
    p = fmaf(p, s, -0.11643287f);
    p = fmaf(p, s,  0.19354346f);
    p = fmaf(p, s, -0.33262348f);
    p = fmaf(p, s,  0.99997726f);
    float a = t * p;
    a = big ? (1.57079632679489662f - a) : a;
    a = copysignf(a, r);
    if (x < 0.f) a += 3.14159274101257324f;
    else if (x > 0.f && y < 0.f) a += 6.28318548202514648f;
    return a * 0.15915494309189535f;
}

// block = 256 threads. Result valid in thread 0.
static __device__ __forceinline__ void block_reduce2(double& a, double& b) {
    for (int o = 32; o; o >>= 1) { a += __shfl_down(a, o); b += __shfl_down(b, o); }
    __shared__ double sa[4], sb[4];
    int wave = threadIdx.x >> 6, lane = threadIdx.x & 63;
    if (lane == 0) { sa[wave] = a; sb[wave] = b; }
    __syncthreads();
    if (threadIdx.x == 0) {
        a = sa[0] + sa[1] + sa[2] + sa[3];
        b = sb[0] + sb[1] + sb[2] + sb[3];
    }
    __syncthreads();
}

// ---------- main fused pass ----------
// Per pixel-group j (4 px), loop n: term, per-(n,seg) count/term-sum (LDS),
// loss (=term where gt==0) -> lossBuf, level-1 8-bit hist of nonzero loss (LDS),
// tsum = sum_n term -> bf16 buffer.
__global__ __launch_bounds__(256) void k_fused(const float* __restrict__ pred,
        const float* __restrict__ gdf, const int* __restrict__ gt,
        float* __restrict__ lossBuf, unsigned short* __restrict__ tsumBuf,
        unsigned* __restrict__ h1G, unsigned* __restrict__ segCG,
        float* __restrict__ segSG) {
    __shared__ unsigned h1[NBATCH * 256];
    __shared__ unsigned sC[4][NBATCH * NSEG];
    __shared__ float    sS[4][NBATCH * NSEG];
    int tid = threadIdx.x, wave = tid >> 6;
    for (int i = tid; i < NBATCH * 256; i += 256) h1[i] = 0u;
    if (tid < NBATCH * NSEG) {
#pragma unroll
        for (int w = 0; w < 4; ++w) { sC[w][tid] = 0u; sS[w][tid] = 0.f; }
    }
    __syncthreads();

    int j = blockIdx.x * 256 + tid;          // 0 .. NGRP-1 (grid exactly covers)
    float4 tsum = make_float4(0.f, 0.f, 0.f, 0.f);
#pragma unroll 2
    for (int n = 0; n < NBATCH; ++n) {
        float4 px4 = ((const float4*)(pred + ((size_t)(2 * n)    ) * HWN))[j];
        float4 py4 = ((const float4*)(pred + ((size_t)(2 * n) + 1) * HWN))[j];
        float4 gx4 = ((const float4*)(gdf  + ((size_t)(2 * n)    ) * HWN))[j];
        float4 gy4 = ((const float4*)(gdf  + ((size_t)(2 * n) + 1) * HWN))[j];
        int4   g4  = ((const int4*)  (gt   + (size_t)n * HWN))[j];
        float4 lossv;
#pragma unroll
        for (int e = 0; e < 4; ++e) {
            float px = (&px4.x)[e], py = (&py4.x)[e];
            float gx = (&gx4.x)[e], gy = (&gy4.x)[e];
            int   g  = (&g4.x)[e] & 15;
            float dx = px - gx, dy = py - gy;
            float ang = polar01(gx, gy) - polar01(px, py);
            float t = dx * dx + dy * dy + ang * ang;
            (&tsum.x)[e] += t;
            atomicAdd(&sC[wave][n * NSEG + g], 1u);
            atomicAdd(&sS[wave][n * NSEG + g], t);
            float lv = (g == 0) ? t : 0.f;
            (&lossv.x)[e] = lv;
            unsigned u = __float_as_uint(lv);
            if (u) atomicAdd(&h1[n * 256 + (u >> 24)], 1u);
        }
        ((float4*)(lossBuf + (size_t)n * HWN))[j] = lossv;
    }
    // tsum -> bf16 (RNE)
    ushort4 tz;
#pragma unroll
    for (int e = 0; e < 4; ++e) {
        unsigned u = __float_as_uint((&tsum.x)[e]);
        (&tz.x)[e] = (unsigned short)((u + 0x7FFFu + ((u >> 16) & 1u)) >> 16);
    }
    ((ushort4*)tsumBuf)[j] = tz;

    __syncthreads();
    int copy = blockIdx.x & 31;   // 32-way replicated global accumulators
    if (tid < NBATCH * NSEG) {
        unsigned c = sC[0][tid] + sC[1][tid] + sC[2][tid] + sC[3][tid];
        float    s = sS[0][tid] + sS[1][tid] + sS[2][tid] + sS[3][tid];
        atomicAdd(&segCG[copy * (NBATCH * NSEG) + tid], c);
        atomicAdd(&segSG[copy * (NBATCH * NSEG) + tid], s);
    }
    for (int i = tid; i < NBATCH * 256; i += 256) {
        unsigned v = h1[i];
        if (v) atomicAdd(&h1G[copy * 2048 + i], v);
    }
}

// ---------- per-sample stats + level-1 scan ----------
// stMode: 0=done, L=needs refine level L. stPfx: prefix bits so far. stK: rank
// from top within current bucket. stT: final uint threshold (u>=T && u!=0 kept).
__global__ void k_scanA(const unsigned* __restrict__ h1G, const unsigned* __restrict__ segCG,
                        const float* __restrict__ segSG, unsigned* __restrict__ stMode,
                        unsigned* __restrict__ stPfx, unsigned* __restrict__ stK,
                        unsigned* __restrict__ stT, double* __restrict__ num1w) {
    int n = blockIdx.x, tid = threadIdx.x;
    __shared__ unsigned h[256];
    __shared__ unsigned cc[NSEG];
    __shared__ double   sd[NSEG];
    unsigned hv = 0;
    for (int c = 0; c < 32; ++c) hv += h1G[c * 2048 + n * 256 + tid];
    h[tid] = hv;
    if (tid < NSEG) {
        unsigned cv = 0; double sv = 0.0;
        for (int c = 0; c < 32; ++c) {
            cv += segCG[c * (NBATCH * NSEG) + n * NSEG + tid];
            sv += (double)segSG[c * (NBATCH * NSEG) + n * NSEG + tid];
        }
        cc[tid] = cv; sd[tid] = sv;
    }
    __syncthreads();
    if (tid == 0) {
        long long sumPos = 0; int nseg = 0;
        for (int s = 1; s < NSEG; ++s) { sumPos += cc[s]; nseg += cc[s] ? 1 : 0; }
        long long sumNeg = cc[0];
        float seg_ave = (float)sumPos / (float)(nseg ? nseg : 1);
        double num1 = 0.0, wsum = 0.0;
        for (int s = 1; s < NSEG; ++s) {
            float pix = seg_ave / (float)(cc[s] ? cc[s] : 1u);
            num1 += (double)pix * sd[s];
            wsum += (double)pix * (double)cc[s];
        }
        num1w[2 * n] = num1; num1w[2 * n + 1] = wsum;
        long long k = 3 * sumPos; if (sumNeg < k) k = sumNeg;
        unsigned nnz = 0;
        for (int b = 0; b < 256; ++b) nnz += h[b];
        if (k <= 0)                      { stMode[n] = 0u; stT[n] = 0xFFFFFFFFu; stPfx[n] = 0u; stK[n] = 0u; }
        else if (k >= (long long)nnz)    { stMode[n] = 0u; stT[n] = 0u;          stPfx[n] = 0u; stK[n] = 0u; }
        else {
            unsigned cum = 0; int b1 = 0;
            for (int b = 255; b >= 0; --b) { if (cum + h[b] >= (unsigned)k) { b1 = b; break; } cum += h[b]; }
            stMode[n] = 1u; stPfx[n] = (unsigned)b1; stK[n] = (unsigned)k - cum; stT[n] = 0u;
        }
    }
}

// ---------- generic 8-bit refinement (levels 1..3), early-exits when done ----------
__global__ __launch_bounds__(256) void k_refine(const float* __restrict__ lossBuf,
        const unsigned* __restrict__ stMode, const unsigned* __restrict__ stPfx,
        unsigned* __restrict__ hist, int level) {
    unsigned md[NBATCH], pf[NBATCH]; bool any = false;
#pragma unroll
    for (int n = 0; n < NBATCH; ++n) {
        md[n] = stMode[n]; pf[n] = stPfx[n];
        any = any || (md[n] == (unsigned)level);
    }
    if (!any) return;   // uniform
    int ms = 32 - 8 * level, hs = 24 - 8 * level;
    int stride = gridDim.x * blockDim.x;
    for (int j = blockIdx.x * blockDim.x + threadIdx.x; j < NGRP; j += stride) {
#pragma unroll
        for (int n = 0; n < NBATCH; ++n) {
            if (md[n] != (unsigned)level) continue;
            float4 lv = ((const float4*)(lossBuf + (size_t)n * HWN))[j];
#pragma unroll
            for (int e = 0; e < 4; ++e) {
                unsigned u = __float_as_uint((&lv.x)[e]);
                if (u != 0u && (u >> ms) == pf[n])
                    atomicAdd(&hist[n * 256 + ((u >> hs) & 255u)], 1u);
            }
        }
    }
}

__global__ void k_scanN(unsigned* __restrict__ stMode, unsigned* __restrict__ stPfx,
                        unsigned* __restrict__ stK, unsigned* __restrict__ stT,
                        const unsigned* __restrict__ hist, int level) {
    int n = blockIdx.x;
    if (stMode[n] != (unsigned)level) return;   // uniform
    __shared__ unsigned h[256];
    h[threadIdx.x] = hist[n * 256 + threadIdx.x];
    __syncthreads();
    if (threadIdx.x == 0) {
        unsigned k2 = stK[n], cum = 0; int bb = 0;
        for (int b = 255; b >= 0; --b) { if (cum + h[b] >= k2) { bb = b; break; } cum += h[b]; }
        unsigned np = (stPfx[n] << 8) | (unsigned)bb;
        stK[n] = k2 - cum;
        if (level == 3) { stT[n] = np; stMode[n] = 0u; }
        else            { stPfx[n] = np; stMode[n] = (unsigned)(level + 1); }
    }
}

// ---------- num2 = sum over kept (n,j) of tsum[j]; msum = count kept ----------
__global__ __launch_bounds__(256) void k_num2(const float* __restrict__ lossBuf,
        const unsigned short* __restrict__ tsumBuf, const unsigned* __restrict__ stT,
        double* __restrict__ partB) {
    unsigned T[NBATCH];
#pragma unroll
    for (int n = 0; n < NBATCH; ++n) T[n] = stT[n];
    double acc = 0.0, cnt = 0.0;
    int stride = gridDim.x * blockDim.x;
    for (int j = blockIdx.x * blockDim.x + threadIdx.x; j < NGRP; j += stride) {
        ushort4 tz = ((const ushort4*)tsumBuf)[j];
        float ts[4];
#pragma unroll
        for (int e = 0; e < 4; ++e) ts[e] = __uint_as_float(((unsigned)(&tz.x)[e]) << 16);
#pragma unroll
        for (int n = 0; n < NBATCH; ++n) {
            float4 lv = ((const float4*)(lossBuf + (size_t)n * HWN))[j];
#pragma unroll
            for (int e = 0; e < 4; ++e) {
                unsigned u = __float_as_uint((&lv.x)[e]);
                if (u != 0u && u >= T[n]) { acc += (double)ts[e]; cnt += 1.0; }
            }
        }
    }
    block_reduce2(acc, cnt);
    if (threadIdx.x == 0) { partB[blockIdx.x * 2] = acc; partB[blockIdx.x * 2 + 1] = cnt; }
}

__global__ void k_result(const double* __restrict__ num1w, const double* __restrict__ partB,
                         float* __restrict__ out) {
    double c = 0.0, d = 0.0;
    for (int i = threadIdx.x; i < N2B; i += 256) { c += partB[2 * i]; d += partB[2 * i + 1]; }
    block_reduce2(c, d);
    if (threadIdx.x == 0) {
        double num1 = 0.0, wsum = 0.0;
        for (int n = 0; n < NBATCH; ++n) { num1 += num1w[2 * n]; wsum += num1w[2 * n + 1]; }
        double num = (double)NBATCH * num1 + c;
        double denom = (double)NBATCH * (wsum + d);
        out[0] = (float)(num / (double)NBATCH / 2.0 / denom);
    }
}

// ---------- launcher ----------

extern "C" void kernel_launch(void* const* d_in, const int* in_sizes, int n_in,
                              void* d_out, int out_size, void* d_ws, size_t ws_size,
                              hipStream_t stream) {
    const float* pred = (const float*)d_in[0];
    const float* gdf  = (const float*)d_in[1];
    const int*   gt   = (const int*)d_in[2];
    float* out = (float*)d_out;

    char* W = (char*)d_ws;
    float* lossBuf = (float*)W;                                   // 32 MiB
    unsigned short* tsumBuf = (unsigned short*)(W + 33554432);    // 2 MiB
    char* Z = W + 33554432 + 2097152;                             // zeroed region
    unsigned* h1G   = (unsigned*)Z;                               // 32*2048*4 = 256 KiB
    unsigned* segCG = (unsigned*)(Z + 262144);                    // 32*128*4 = 16 KiB
    float*    segSG = (float*)  (Z + 262144 + 16384);             // 16 KiB
    unsigned* hA    = (unsigned*)(Z + 262144 + 32768);            // 8 KiB
    unsigned* hB    = hA + 2048;                                  // 8 KiB
    unsigned* hC    = hB + 2048;                                  // 8 KiB
    const size_t ZBYTES = 262144 + 32768 + 3 * 8192;
    char* P = Z + ZBYTES;
    unsigned* stMode = (unsigned*)P;          // 8
    unsigned* stPfx  = stMode + 8;            // 8
    unsigned* stK    = stMode + 16;           // 8
    unsigned* stT    = stMode + 24;           // 8
    double* num1w    = (double*)(P + 128);    // 16 doubles
    double* partB    = (double*)(P + 256);    // N2B*2 doubles = 8 KiB

    size_t need = 33554432 + 2097152 + ZBYTES + 256 + (size_t)N2B * 2 * 8;
    if (ws_size < need) return;

    hipMemsetAsync(Z, 0, ZBYTES, stream);
    k_fused <<<dim3(NGRP / 256), 256, 0, stream>>>(pred, gdf, gt, lossBuf, tsumBuf, h1G, segCG, segSG);
    k_scanA <<<NBATCH, 256, 0, stream>>>(h1G, segCG, segSG, stMode, stPfx, stK, stT, num1w);
    k_refine<<<256, 256, 0, stream>>>(lossBuf, stMode, stPfx, hA, 1);
    k_scanN <<<NBATCH, 256, 0, stream>>>(stMode, stPfx, stK, stT, hA, 1);
    k_refine<<<256, 256, 0, stream>>>(lossBuf, stMode, stPfx, hB, 2);
    k_scanN <<<NBATCH, 256, 0, stream>>>(stMode, stPfx, stK, stT, hB, 2);
    k_refine<<<256, 256, 0, stream>>>(lossBuf, stMode, stPfx, hC, 3);
    k_scanN <<<NBATCH, 256, 0, stream>>>(stMode, stPfx, stK, stT, hC, 3);
    k_num2  <<<N2B, 256, 0, stream>>>(lossBuf, tsumBuf, stT, partB);
    k_result<<<1, 256, 0, stream>>>(num1w, partB, out);
}